// Round 11
// baseline (311.383 us; speedup 1.0000x reference)
//
#include <hip/hip_runtime.h>
#include <math.h>

#define NEG_SLOPE 0.2f

typedef unsigned short ushort_t;
typedef __attribute__((ext_vector_type(8))) short short8;
typedef __attribute__((ext_vector_type(4))) float float4v;
typedef _Float16 half2v __attribute__((ext_vector_type(2)));

#if defined(__has_builtin)
#if __has_builtin(__builtin_amdgcn_fdot2)
#define HAS_FDOT2 1
#endif
#endif

__device__ __forceinline__ ushort_t f2bf(float f) {           // RNE
    unsigned u = __float_as_uint(f);
    return (ushort_t)((u + 0x7fffu + ((u >> 16) & 1u)) >> 16);
}
__device__ __forceinline__ unsigned pack2bf(float lo, float hi) {
    return ((unsigned)f2bf(hi) << 16) | (unsigned)f2bf(lo);
}

// ================= CSR build =================
__global__ void hist_kernel(const int* __restrict__ dst, int* __restrict__ deg, int E) {
    int i = blockIdx.x * 256 + threadIdx.x;
    if (i < E) atomicAdd(&deg[dst[i]], 1);
}

__global__ void partial_kernel(const int* __restrict__ deg, int* __restrict__ partial, int n) {
    const int t = threadIdx.x;
    const int i = blockIdx.x * 256 + t;
    int v = (i < n) ? deg[i] : 0;
#pragma unroll
    for (int off = 32; off > 0; off >>= 1) v += __shfl_xor(v, off, 64);
    __shared__ int ws[4];
    if ((t & 63) == 0) ws[t >> 6] = v;
    __syncthreads();
    if (t == 0) partial[blockIdx.x] = ws[0] + ws[1] + ws[2] + ws[3];
}

__global__ void scan_kernel(const int* __restrict__ in, int* __restrict__ out, int n) {
    __shared__ int sm[1024];
    __shared__ int carry_s;
    const int t = threadIdx.x;
    if (t == 0) { carry_s = 0; out[0] = 0; }
    __syncthreads();
    for (int base = 0; base < n; base += 1024) {
        int v = (base + t < n) ? in[base + t] : 0;
        sm[t] = v;
        __syncthreads();
        for (int off = 1; off < 1024; off <<= 1) {
            int u = (t >= off) ? sm[t - off] : 0;
            __syncthreads();
            sm[t] += u;
            __syncthreads();
        }
        if (base + t < n) out[base + t + 1] = carry_s + sm[t];
        __syncthreads();
        if (t == 0) carry_s += sm[1023];
        __syncthreads();
    }
}

__global__ void scan_block_kernel(const int* __restrict__ deg, const int* __restrict__ blk_off,
                                  int* __restrict__ row_ptr, int n) {
    const int t = threadIdx.x;
    const int i = blockIdx.x * 256 + t;
    const int lane = t & 63, w = t >> 6;
    int x = (i < n) ? deg[i] : 0;
#pragma unroll
    for (int off = 1; off < 64; off <<= 1) {
        int u = __shfl_up(x, off, 64);
        if (lane >= off) x += u;
    }
    __shared__ int ws[4];
    if (lane == 63) ws[w] = x;
    __syncthreads();
    int add = blk_off[blockIdx.x];
#pragma unroll
    for (int j = 0; j < 4; ++j)
        if (j < w) add += ws[j];
    if (i < n) row_ptr[i + 1] = add + x;
    if (i == 0) row_ptr[0] = 0;
}

__global__ void scatter_kernel(const int* __restrict__ src, const int* __restrict__ dst,
                               const int* __restrict__ row_ptr, int* __restrict__ cursor,
                               int* __restrict__ csr_src, int E) {
    int i = blockIdx.x * 256 + threadIdx.x;
    if (i < E) {
        int d = dst[i];
        int pos = row_ptr[d] + atomicAdd(&cursor[d], 1);
        csr_src[pos] = src[i];
    }
}

// ===== degree-balanced node order: counting sort by degree, DESCENDING =====
__global__ void dhist_kernel(const int* __restrict__ row_ptr, int* __restrict__ dhist, int n) {
    int i = blockIdx.x * 256 + threadIdx.x;
    if (i < n) {
        int dg = row_ptr[i + 1] - row_ptr[i];
        int b = 511 - min(dg, 511);           // descending degree
        atomicAdd(&dhist[b], 1);
    }
}

__global__ void dscan_kernel(const int* __restrict__ dhist, int* __restrict__ doff) {
    __shared__ int sm[512];
    const int t = threadIdx.x;                // 512 threads
    const int v = dhist[t];
    sm[t] = v;
    __syncthreads();
    for (int off = 1; off < 512; off <<= 1) {
        int u = (t >= off) ? sm[t - off] : 0;
        __syncthreads();
        sm[t] += u;
        __syncthreads();
    }
    doff[t] = sm[t] - v;                      // exclusive
}

__global__ void dscatter_kernel(const int* __restrict__ row_ptr, const int* __restrict__ doff,
                                int* __restrict__ dcursor, int* __restrict__ order, int n) {
    int i = blockIdx.x * 256 + threadIdx.x;
    if (i < n) {
        int dg = row_ptr[i + 1] - row_ptr[i];
        int b = 511 - min(dg, 511);
        int pos = doff[b] + atomicAdd(&dcursor[b], 1);
        order[pos] = i;
    }
}

// ======= all four weight transposes in ONE launch: WT[c][k] = bf16(W[k][c]) =======
__global__ void wt_all_kernel(const float* __restrict__ W1l, const float* __restrict__ W1r,
                              const float* __restrict__ W2l, const float* __restrict__ W2r,
                              ushort_t* __restrict__ T1l, ushort_t* __restrict__ T1r,
                              ushort_t* __restrict__ T2l, ushort_t* __restrict__ T2r) {
    const int b = blockIdx.x;
    const float* W;
    ushort_t* T;
    int K, idx;
    if (b < 64)       { W = W1l; T = T1l; K = 64;  idx = b * 256 + threadIdx.x; }
    else if (b < 128) { W = W1r; T = T1r; K = 64;  idx = (b - 64) * 256 + threadIdx.x; }
    else if (b < 384) { W = W2l; T = T2l; K = 256; idx = (b - 128) * 256 + threadIdx.x; }
    else              { W = W2r; T = T2r; K = 256; idx = (b - 384) * 256 + threadIdx.x; }
    const int k = idx >> 8, c = idx & 255;
    T[(size_t)c * K + k] = f2bf(W[idx]);
}

// ====== dual MFMA GEMM (double-buffered LDS): outl/outr both fp16 ==================
template <int K, bool A_FP32>
__global__ __launch_bounds__(256) void gemm_dual_kernel(const void* __restrict__ Av,
                                                        const ushort_t* __restrict__ BTl,
                                                        const ushort_t* __restrict__ BTr,
                                                        const float* __restrict__ bl,
                                                        const float* __restrict__ br,
                                                        _Float16* __restrict__ outl,
                                                        _Float16* __restrict__ outr, int M) {
    __shared__ ushort_t As[2][64][40];       // [buf][row][k]
    __shared__ ushort_t Bs[2][2][128][40];   // [buf][mat][col][k]
    const int t = threadIdx.x;
    const int row0 = blockIdx.x * 64, col0 = blockIdx.y * 128;
    const int wid = t >> 6, lane = t & 63;
    const int wr = wid >> 1, wc = wid & 1;
    const int frow = lane & 15, fk = (lane >> 4) * 8;
    const int arow = t >> 2, ak8 = (t & 3) * 8;
    const int srow = t >> 1, sks = (t & 1) * 16;

    float4v acc[2][2][4];
#pragma unroll
    for (int m = 0; m < 2; ++m)
#pragma unroll
        for (int i = 0; i < 2; ++i)
#pragma unroll
            for (int j = 0; j < 4; ++j) acc[m][i][j] = (float4v){0.f, 0.f, 0.f, 0.f};

    auto stage = [&](int buf, int k0) {
        uint4 va = make_uint4(0, 0, 0, 0);
        if (row0 + arow < M) {
            if (A_FP32) {
                const float* Xf = (const float*)Av + (size_t)(row0 + arow) * K + k0 + ak8;
                float4 x0 = *(const float4*)(Xf + 0);
                float4 x1 = *(const float4*)(Xf + 4);
                va = make_uint4(pack2bf(x0.x, x0.y), pack2bf(x0.z, x0.w),
                                pack2bf(x1.x, x1.y), pack2bf(x1.z, x1.w));
            } else {
                va = *(const uint4*)((const ushort_t*)Av + (size_t)(row0 + arow) * K + k0 + ak8);
            }
        }
        *(uint4*)&As[buf][arow][ak8] = va;
        const ushort_t* Bp = BTl + (size_t)(col0 + srow) * K + k0 + sks;
        *(uint4*)&Bs[buf][0][srow][sks + 0] = *(const uint4*)(Bp + 0);
        *(uint4*)&Bs[buf][0][srow][sks + 8] = *(const uint4*)(Bp + 8);
        const ushort_t* Bq = BTr + (size_t)(col0 + srow) * K + k0 + sks;
        *(uint4*)&Bs[buf][1][srow][sks + 0] = *(const uint4*)(Bq + 0);
        *(uint4*)&Bs[buf][1][srow][sks + 8] = *(const uint4*)(Bq + 8);
    };

    stage(0, 0);
    __syncthreads();
    int cur = 0;
    for (int k0 = 0; k0 < K; k0 += 32) {
        if (k0 + 32 < K) stage(cur ^ 1, k0 + 32);   // loads hide under MFMA below
        short8 af[2], bf[2][4];
#pragma unroll
        for (int mi = 0; mi < 2; ++mi)
            af[mi] = *(const short8*)&As[cur][wr * 32 + mi * 16 + frow][fk];
#pragma unroll
        for (int m = 0; m < 2; ++m)
#pragma unroll
            for (int ni = 0; ni < 4; ++ni)
                bf[m][ni] = *(const short8*)&Bs[cur][m][wc * 64 + ni * 16 + frow][fk];
#pragma unroll
        for (int m = 0; m < 2; ++m)
#pragma unroll
            for (int mi = 0; mi < 2; ++mi)
#pragma unroll
                for (int ni = 0; ni < 4; ++ni)
                    acc[m][mi][ni] = __builtin_amdgcn_mfma_f32_16x16x32_bf16(
                        af[mi], bf[m][ni], acc[m][mi][ni], 0, 0, 0);
        __syncthreads();
        cur ^= 1;
    }

    const int crow = (lane >> 4) * 4;
#pragma unroll
    for (int ni = 0; ni < 4; ++ni) {
        const int col = col0 + wc * 64 + ni * 16 + frow;
        const float bvl = bl[col], bvr = br[col];
#pragma unroll
        for (int mi = 0; mi < 2; ++mi) {
#pragma unroll
            for (int r = 0; r < 4; ++r) {
                const int row = row0 + wr * 32 + mi * 16 + crow + r;
                if (row < M) {
                    outl[(size_t)row * 256 + col] = (_Float16)(acc[0][mi][ni][r] + bvl);
                    outr[(size_t)row * 256 + col] = (_Float16)(acc[1][mi][ni][r] + bvr);
                }
            }
        }
    }
}

// ============ fused GAT: ONE WAVE per node (degree-balanced order), 1-deep prefetch ==
// lane = e*32 + g: e = edge slot 0..1, g = channel group 0..31 (head = g>>3).
__global__ __launch_bounds__(256) void gat_fused_kernel(const int* __restrict__ order,
                                                        const int* __restrict__ csr_src,
                                                        const int* __restrict__ row_ptr,
                                                        const _Float16* __restrict__ xl,
                                                        const _Float16* __restrict__ xr,
                                                        const float* __restrict__ att,
                                                        const float* __restrict__ bias,
                                                        ushort_t* __restrict__ out_b,
                                                        float* __restrict__ out,
                                                        float* __restrict__ out_ls,
                                                        int n_nodes, int apply_elu) {
    const int wv = threadIdx.x >> 6;
    const int gi = blockIdx.x * 4 + wv;
    if (gi >= n_nodes) return;           // wave-uniform
    const int d = order[gi];
    const int lane = threadIdx.x & 63;
    const int e = lane >> 5;             // edge slot 0..1
    const int g = lane & 31;             // channel group (covers all 4 heads)
    const int off = g * 8;               // flat channel offset 0..255 step 8

    union U8 { uint4 u; _Float16 h[8]; half2v h2[4]; };
    U8 xru;
    xru.u = *(const uint4*)(xr + (size_t)d * 256 + off);
    float avf[8];
    *(float4*)&avf[0] = *(const float4*)(att + off);
    *(float4*)&avf[4] = *(const float4*)(att + off + 4);
#if HAS_FDOT2
    half2v xr2[4], a06[4], a04[4];       // lrelu(v)*a = (0.6a)*v + (0.4a)*|v|
#pragma unroll
    for (int i = 0; i < 4; ++i) {
        xr2[i] = xru.h2[i];
        a06[i] = (half2v){(_Float16)(0.6f * avf[2 * i]), (_Float16)(0.6f * avf[2 * i + 1])};
        a04[i] = (half2v){(_Float16)(0.4f * avf[2 * i]), (_Float16)(0.4f * avf[2 * i + 1])};
    }
#else
    float xrf[8];
#pragma unroll
    for (int i = 0; i < 8; ++i) xrf[i] = (float)xru.h[i];
#endif
    const int e0 = row_ptr[d];
    const int deg = row_ptr[d + 1] - e0;
    const int cnt = deg + 1;             // + self loop at index deg
    const int nchunk = (cnt + 1) >> 1;   // 2 edges per chunk
    float m = -INFINITY, s_loc = 0.f;
    float acc8[8] = {0.f, 0.f, 0.f, 0.f, 0.f, 0.f, 0.f, 0.f};

    // ---- pipeline prologue: gather chunk 0, index for chunk 1 ----
    U8 gc;
    {
        const int j = e;
        const int sn = (j < deg) ? csr_src[e0 + j] : d;
        gc.u = *(const uint4*)(xl + (size_t)sn * 256 + off);
    }
    int sn_nxt = d;
    if (nchunk > 1) {
        const int j = 2 + e;
        sn_nxt = (j < deg) ? csr_src[e0 + j] : d;
    }

    for (int c = 0; c < nchunk; ++c) {
        const int base = c << 1;
        // prefetch: index for chunk c+2
        int sn_n2 = d;
        if (c + 2 < nchunk) {
            const int j = base + 4 + e;
            sn_n2 = (j < deg) ? csr_src[e0 + j] : d;
        }
        // prefetch: gather for chunk c+1
        U8 gn;
        gn.u = make_uint4(0, 0, 0, 0);
        if (c + 1 < nchunk) gn.u = *(const uint4*)(xl + (size_t)sn_nxt * 256 + off);

        // ---- compute on chunk c ----
        const int j = base + e;
        float sc = 0.f;
#if HAS_FDOT2
#pragma unroll
        for (int i = 0; i < 4; ++i) {
            half2v v = gc.h2[i] + xr2[i];                      // v_pk_add_f16
            unsigned vb = __builtin_bit_cast(unsigned, v);
            half2v va = __builtin_bit_cast(half2v, vb & 0x7fff7fffu);  // packed |v|
            sc = __builtin_amdgcn_fdot2(v, a06[i], sc, false);
            sc = __builtin_amdgcn_fdot2(va, a04[i], sc, false);
        }
#else
#pragma unroll
        for (int i = 0; i < 8; ++i) {
            float v = (float)gc.h[i] + xrf[i];
            v = fmaxf(v, NEG_SLOPE * v);
            sc = fmaf(v, avf[i], sc);
        }
#endif
        // reduce over the 8 channel-groups of this head
        sc += __shfl_xor(sc, 1, 64);
        sc += __shfl_xor(sc, 2, 64);
        sc += __shfl_xor(sc, 4, 64);     // lane holds full score of (edge j, its head)
        sc = (j < cnt) ? sc : -INFINITY; // mask pad edge
        // per-head chunk max over the 2 edge slots
        float mx = fmaxf(sc, __shfl_xor(sc, 32, 64));
        if (mx > m + 8.f) {              // defer-rescale: p bounded by e^8
            const float g2f = __expf(m - mx);
            s_loc *= g2f;
#pragma unroll
            for (int i = 0; i < 8; ++i) acc8[i] *= g2f;
            m = mx;
        }
        const float p = __expf(sc - m);  // pad -> 0
        s_loc += p;
#pragma unroll
        for (int i = 0; i < 8; ++i)      // fp16 src -> v_fma_mix
            acc8[i] = fmaf(p, (float)gc.h[i], acc8[i]);

        gc = gn;
        sn_nxt = sn_n2;
    }

    // reduce across the 2 edge slots (once per node)
    float s_tot = s_loc + __shfl_xor(s_loc, 32, 64);
#pragma unroll
    for (int i = 0; i < 8; ++i) acc8[i] += __shfl_xor(acc8[i], 32, 64);
    const float inv_s = 1.f / s_tot;
    float o8[8];
    const float* bp = bias + off;
#pragma unroll
    for (int i = 0; i < 8; ++i) o8[i] = acc8[i] * inv_s + bp[i];

    if (apply_elu) {
#pragma unroll
        for (int i = 0; i < 8; ++i) o8[i] = o8[i] > 0.f ? o8[i] : (__expf(o8[i]) - 1.f);
        if (e == 0) {                    // 32 lanes x 16B = 512B contiguous
            uint4 u;
            u.x = pack2bf(o8[0], o8[1]);
            u.y = pack2bf(o8[2], o8[3]);
            u.z = pack2bf(o8[4], o8[5]);
            u.w = pack2bf(o8[6], o8[7]);
            *(uint4*)(out_b + (size_t)d * 256 + off) = u;
        }
    } else {
        if (e == 0) {
            float* op = out + (size_t)d * 256 + off;
            *(float4*)op       = make_float4(o8[0], o8[1], o8[2], o8[3]);
            *(float4*)(op + 4) = make_float4(o8[4], o8[5], o8[6], o8[7]);
        }
        // fused row log_softmax over all 256 channels — pure shfl, no LDS
        float mx = o8[0];
#pragma unroll
        for (int i = 1; i < 8; ++i) mx = fmaxf(mx, o8[i]);
        mx = fmaxf(mx, __shfl_xor(mx, 1, 64));
        mx = fmaxf(mx, __shfl_xor(mx, 2, 64));
        mx = fmaxf(mx, __shfl_xor(mx, 4, 64));
        mx = fmaxf(mx, __shfl_xor(mx, 8, 64));
        mx = fmaxf(mx, __shfl_xor(mx, 16, 64));   // row max (o8 replicated across e)
        float se = 0.f;
#pragma unroll
        for (int i = 0; i < 8; ++i) se += __expf(o8[i] - mx);
        se += __shfl_xor(se, 1, 64);
        se += __shfl_xor(se, 2, 64);
        se += __shfl_xor(se, 4, 64);
        se += __shfl_xor(se, 8, 64);
        se += __shfl_xor(se, 16, 64);
        const float lg = mx + __logf(se);
        if (e == 0) {
            float* lp = out_ls + (size_t)d * 256 + off;
            *(float4*)lp       = make_float4(o8[0] - lg, o8[1] - lg, o8[2] - lg, o8[3] - lg);
            *(float4*)(lp + 4) = make_float4(o8[4] - lg, o8[5] - lg, o8[6] - lg, o8[7] - lg);
        }
    }
}

extern "C" void kernel_launch(void* const* d_in, const int* in_sizes, int n_in,
                              void* d_out, int out_size, void* d_ws, size_t ws_size,
                              hipStream_t stream) {
    const float* x     = (const float*)d_in[0];
    const int*   edge  = (const int*)d_in[1];
    const float* Wl1   = (const float*)d_in[2];
    const float* bl1   = (const float*)d_in[3];
    const float* Wr1   = (const float*)d_in[4];
    const float* br1   = (const float*)d_in[5];
    const float* att1  = (const float*)d_in[6];
    const float* bias1 = (const float*)d_in[7];
    const float* Wl2   = (const float*)d_in[8];
    const float* bl2   = (const float*)d_in[9];
    const float* Wr2   = (const float*)d_in[10];
    const float* br2   = (const float*)d_in[11];
    const float* att2  = (const float*)d_in[12];
    const float* bias2 = (const float*)d_in[13];

    const int N = in_sizes[0] / 64;  // 20000
    const int E = in_sizes[1] / 2;   // 500000
    const int* srcI = edge;
    const int* dstI = edge + E;

    const size_t NM = (size_t)N * 256;
    _Float16*  XR   = (_Float16*)d_ws;             // NM fp16 (xr)
    ushort_t*  XB   = (ushort_t*)(XR + NM);        // NM bf16 (layer-1 out = layer-2 A)
    _Float16*  XL   = (_Float16*)(XB + NM);        // NM fp16 (xl gather table)
    ushort_t*  WT1l = (ushort_t*)(XL + NM);        // 256*64
    ushort_t*  WT1r = WT1l + 256 * 64;             // 256*64
    ushort_t*  WT2l = WT1r + 256 * 64;             // 256*256
    ushort_t*  WT2r = WT2l + 256 * 256;            // 256*256
    int* deg     = (int*)(WT2r + 256 * 256);       // N
    int* row_ptr = deg + N;                        // N+1
    int* cursor  = row_ptr + N + 1;                // N
    int* partial = cursor + N;                     // nb
    int* blk_off = partial + ((N + 255) / 256);      // nb+1
    int* order   = blk_off + ((N + 255) / 256) + 1;  // N
    int* dhist   = order + N;                      // 512
    int* doff    = dhist + 512;                    // 512
    int* dcursor = doff + 512;                     // 512
    int* csr_src = dcursor + 512;                  // E

    const int nb = (N + 255) / 256;
    const int e_grid = (E + 255) / 256;
    const dim3 gemm_grid((N + 63) / 64, 2);
    const int gat_grid = (N + 3) / 4;

    // ---- weight transposes to bf16 (one launch) ----
    wt_all_kernel<<<640, 256, 0, stream>>>(Wl1, Wr1, Wl2, Wr2, WT1l, WT1r, WT2l, WT2r);

    // ---- CSR by destination ----
    hipMemsetAsync(deg, 0, (size_t)N * sizeof(int), stream);
    hipMemsetAsync(cursor, 0, (size_t)N * sizeof(int), stream);
    hipMemsetAsync(dhist, 0, 512 * sizeof(int), stream);
    hipMemsetAsync(dcursor, 0, 512 * sizeof(int), stream);
    hist_kernel<<<e_grid, 256, 0, stream>>>(dstI, deg, E);
    partial_kernel<<<nb, 256, 0, stream>>>(deg, partial, N);
    scan_kernel<<<1, 1024, 0, stream>>>(partial, blk_off, nb);
    scan_block_kernel<<<nb, 256, 0, stream>>>(deg, blk_off, row_ptr, N);
    scatter_kernel<<<e_grid, 256, 0, stream>>>(srcI, dstI, row_ptr, cursor, csr_src, E);
    // ---- degree-balanced node order (counting sort, descending) ----
    dhist_kernel<<<nb, 256, 0, stream>>>(row_ptr, dhist, N);
    dscan_kernel<<<1, 512, 0, stream>>>(dhist, doff);
    dscatter_kernel<<<nb, 256, 0, stream>>>(row_ptr, doff, dcursor, order, N);

    // ---- layer 1 (A = x fp32, K=64): one dual GEMM -> XL (fp16) + XR (fp16) ----
    gemm_dual_kernel<64, true><<<gemm_grid, 256, 0, stream>>>(x, WT1l, WT1r, bl1, br1,
                                                              XL, XR, N);
    gat_fused_kernel<<<gat_grid, 256, 0, stream>>>(order, csr_src, row_ptr, XL, XR,
                                                   att1, bias1, XB, nullptr, nullptr, N, 1);

    // ---- layer 2 (A = XB bf16, K=256) ----
    gemm_dual_kernel<256, false><<<gemm_grid, 256, 0, stream>>>(XB, WT2l, WT2r, bl2, br2,
                                                                XL, XR, N);
    float* h2 = (float*)d_out;
    gat_fused_kernel<<<gat_grid, 256, 0, stream>>>(order, csr_src, row_ptr, XL, XR,
                                                   att2, bias2, nullptr, h2, h2 + NM, N, 0);
}

// Round 12
// 208.456 us; speedup vs baseline: 1.4938x; 1.4938x over previous
//
#include <hip/hip_runtime.h>
#include <math.h>

#define NEG_SLOPE 0.2f

typedef unsigned short ushort_t;
typedef __attribute__((ext_vector_type(8))) short short8;
typedef __attribute__((ext_vector_type(4))) float float4v;
typedef _Float16 half2v __attribute__((ext_vector_type(2)));

#if defined(__has_builtin)
#if __has_builtin(__builtin_amdgcn_fdot2)
#define HAS_FDOT2 1
#endif
#endif

__device__ __forceinline__ ushort_t f2bf(float f) {           // RNE
    unsigned u = __float_as_uint(f);
    return (ushort_t)((u + 0x7fffu + ((u >> 16) & 1u)) >> 16);
}
__device__ __forceinline__ unsigned pack2bf(float lo, float hi) {
    return ((unsigned)f2bf(hi) << 16) | (unsigned)f2bf(lo);
}

// ================= CSR build =================
__global__ void hist_kernel(const int* __restrict__ dst, int* __restrict__ deg, int E) {
    int i = blockIdx.x * 256 + threadIdx.x;
    if (i < E) atomicAdd(&deg[dst[i]], 1);
}

__global__ void partial_kernel(const int* __restrict__ deg, int* __restrict__ partial, int n) {
    const int t = threadIdx.x;
    const int i = blockIdx.x * 256 + t;
    int v = (i < n) ? deg[i] : 0;
#pragma unroll
    for (int off = 32; off > 0; off >>= 1) v += __shfl_xor(v, off, 64);
    __shared__ int ws[4];
    if ((t & 63) == 0) ws[t >> 6] = v;
    __syncthreads();
    if (t == 0) partial[blockIdx.x] = ws[0] + ws[1] + ws[2] + ws[3];
}

__global__ void scan_kernel(const int* __restrict__ in, int* __restrict__ out, int n) {
    __shared__ int sm[1024];
    __shared__ int carry_s;
    const int t = threadIdx.x;
    if (t == 0) { carry_s = 0; out[0] = 0; }
    __syncthreads();
    for (int base = 0; base < n; base += 1024) {
        int v = (base + t < n) ? in[base + t] : 0;
        sm[t] = v;
        __syncthreads();
        for (int off = 1; off < 1024; off <<= 1) {
            int u = (t >= off) ? sm[t - off] : 0;
            __syncthreads();
            sm[t] += u;
            __syncthreads();
        }
        if (base + t < n) out[base + t + 1] = carry_s + sm[t];
        __syncthreads();
        if (t == 0) carry_s += sm[1023];
        __syncthreads();
    }
}

__global__ void scan_block_kernel(const int* __restrict__ deg, const int* __restrict__ blk_off,
                                  int* __restrict__ row_ptr, int n) {
    const int t = threadIdx.x;
    const int i = blockIdx.x * 256 + t;
    const int lane = t & 63, w = t >> 6;
    int x = (i < n) ? deg[i] : 0;
#pragma unroll
    for (int off = 1; off < 64; off <<= 1) {
        int u = __shfl_up(x, off, 64);
        if (lane >= off) x += u;
    }
    __shared__ int ws[4];
    if (lane == 63) ws[w] = x;
    __syncthreads();
    int add = blk_off[blockIdx.x];
#pragma unroll
    for (int j = 0; j < 4; ++j)
        if (j < w) add += ws[j];
    if (i < n) row_ptr[i + 1] = add + x;
    if (i == 0) row_ptr[0] = 0;
}

__global__ void scatter_kernel(const int* __restrict__ src, const int* __restrict__ dst,
                               const int* __restrict__ row_ptr, int* __restrict__ cursor,
                               int* __restrict__ csr_src, int E) {
    int i = blockIdx.x * 256 + threadIdx.x;
    if (i < E) {
        int d = dst[i];
        int pos = row_ptr[d] + atomicAdd(&cursor[d], 1);
        csr_src[pos] = src[i];
    }
}

// ======= all four weight transposes in ONE launch: WT[c][k] = bf16(W[k][c]) =======
__global__ void wt_all_kernel(const float* __restrict__ W1l, const float* __restrict__ W1r,
                              const float* __restrict__ W2l, const float* __restrict__ W2r,
                              ushort_t* __restrict__ T1l, ushort_t* __restrict__ T1r,
                              ushort_t* __restrict__ T2l, ushort_t* __restrict__ T2r) {
    const int b = blockIdx.x;
    const float* W;
    ushort_t* T;
    int K, idx;
    if (b < 64)       { W = W1l; T = T1l; K = 64;  idx = b * 256 + threadIdx.x; }
    else if (b < 128) { W = W1r; T = T1r; K = 64;  idx = (b - 64) * 256 + threadIdx.x; }
    else if (b < 384) { W = W2l; T = T2l; K = 256; idx = (b - 128) * 256 + threadIdx.x; }
    else              { W = W2r; T = T2r; K = 256; idx = (b - 384) * 256 + threadIdx.x; }
    const int k = idx >> 8, c = idx & 255;
    T[(size_t)c * K + k] = f2bf(W[idx]);
}

// ====== dual MFMA GEMM (double-buffered LDS): outl/outr both fp16 ==================
template <int K, bool A_FP32>
__global__ __launch_bounds__(256) void gemm_dual_kernel(const void* __restrict__ Av,
                                                        const ushort_t* __restrict__ BTl,
                                                        const ushort_t* __restrict__ BTr,
                                                        const float* __restrict__ bl,
                                                        const float* __restrict__ br,
                                                        _Float16* __restrict__ outl,
                                                        _Float16* __restrict__ outr, int M) {
    __shared__ ushort_t As[2][64][40];       // [buf][row][k]
    __shared__ ushort_t Bs[2][2][128][40];   // [buf][mat][col][k]
    const int t = threadIdx.x;
    const int row0 = blockIdx.x * 64, col0 = blockIdx.y * 128;
    const int wid = t >> 6, lane = t & 63;
    const int wr = wid >> 1, wc = wid & 1;
    const int frow = lane & 15, fk = (lane >> 4) * 8;
    const int arow = t >> 2, ak8 = (t & 3) * 8;
    const int srow = t >> 1, sks = (t & 1) * 16;

    float4v acc[2][2][4];
#pragma unroll
    for (int m = 0; m < 2; ++m)
#pragma unroll
        for (int i = 0; i < 2; ++i)
#pragma unroll
            for (int j = 0; j < 4; ++j) acc[m][i][j] = (float4v){0.f, 0.f, 0.f, 0.f};

    auto stage = [&](int buf, int k0) {
        uint4 va = make_uint4(0, 0, 0, 0);
        if (row0 + arow < M) {
            if (A_FP32) {
                const float* Xf = (const float*)Av + (size_t)(row0 + arow) * K + k0 + ak8;
                float4 x0 = *(const float4*)(Xf + 0);
                float4 x1 = *(const float4*)(Xf + 4);
                va = make_uint4(pack2bf(x0.x, x0.y), pack2bf(x0.z, x0.w),
                                pack2bf(x1.x, x1.y), pack2bf(x1.z, x1.w));
            } else {
                va = *(const uint4*)((const ushort_t*)Av + (size_t)(row0 + arow) * K + k0 + ak8);
            }
        }
        *(uint4*)&As[buf][arow][ak8] = va;
        const ushort_t* Bp = BTl + (size_t)(col0 + srow) * K + k0 + sks;
        *(uint4*)&Bs[buf][0][srow][sks + 0] = *(const uint4*)(Bp + 0);
        *(uint4*)&Bs[buf][0][srow][sks + 8] = *(const uint4*)(Bp + 8);
        const ushort_t* Bq = BTr + (size_t)(col0 + srow) * K + k0 + sks;
        *(uint4*)&Bs[buf][1][srow][sks + 0] = *(const uint4*)(Bq + 0);
        *(uint4*)&Bs[buf][1][srow][sks + 8] = *(const uint4*)(Bq + 8);
    };

    stage(0, 0);
    __syncthreads();
    int cur = 0;
    for (int k0 = 0; k0 < K; k0 += 32) {
        if (k0 + 32 < K) stage(cur ^ 1, k0 + 32);   // loads hide under MFMA below
        short8 af[2], bf[2][4];
#pragma unroll
        for (int mi = 0; mi < 2; ++mi)
            af[mi] = *(const short8*)&As[cur][wr * 32 + mi * 16 + frow][fk];
#pragma unroll
        for (int m = 0; m < 2; ++m)
#pragma unroll
            for (int ni = 0; ni < 4; ++ni)
                bf[m][ni] = *(const short8*)&Bs[cur][m][wc * 64 + ni * 16 + frow][fk];
#pragma unroll
        for (int m = 0; m < 2; ++m)
#pragma unroll
            for (int mi = 0; mi < 2; ++mi)
#pragma unroll
                for (int ni = 0; ni < 4; ++ni)
                    acc[m][mi][ni] = __builtin_amdgcn_mfma_f32_16x16x32_bf16(
                        af[mi], bf[m][ni], acc[m][mi][ni], 0, 0, 0);
        __syncthreads();
        cur ^= 1;
    }

    const int crow = (lane >> 4) * 4;
#pragma unroll
    for (int ni = 0; ni < 4; ++ni) {
        const int col = col0 + wc * 64 + ni * 16 + frow;
        const float bvl = bl[col], bvr = br[col];
#pragma unroll
        for (int mi = 0; mi < 2; ++mi) {
#pragma unroll
            for (int r = 0; r < 4; ++r) {
                const int row = row0 + wr * 32 + mi * 16 + crow + r;
                if (row < M) {
                    outl[(size_t)row * 256 + col] = (_Float16)(acc[0][mi][ni][r] + bvl);
                    outr[(size_t)row * 256 + col] = (_Float16)(acc[1][mi][ni][r] + bvr);
                }
            }
        }
    }
}

// ============ fused GAT: ONE WAVE per node, 2 waves per block, 1-deep prefetch ======
// lane = e*32 + g: e = edge slot 0..1, g = channel group 0..31 (head = g>>3).
__global__ __launch_bounds__(128) void gat_fused_kernel(const int* __restrict__ csr_src,
                                                        const int* __restrict__ row_ptr,
                                                        const _Float16* __restrict__ xl,
                                                        const _Float16* __restrict__ xr,
                                                        const float* __restrict__ att,
                                                        const float* __restrict__ bias,
                                                        ushort_t* __restrict__ out_b,
                                                        float* __restrict__ out,
                                                        float* __restrict__ out_ls,
                                                        int n_nodes, int apply_elu) {
    const int wv = threadIdx.x >> 6;
    const int d = blockIdx.x * 2 + wv;
    if (d >= n_nodes) return;            // wave-uniform, no barriers anywhere
    const int lane = threadIdx.x & 63;
    const int e = lane >> 5;             // edge slot 0..1
    const int g = lane & 31;             // channel group (covers all 4 heads)
    const int off = g * 8;               // flat channel offset 0..255 step 8

    union U8 { uint4 u; _Float16 h[8]; half2v h2[4]; };
    U8 xru;
    xru.u = *(const uint4*)(xr + (size_t)d * 256 + off);
    float avf[8];
    *(float4*)&avf[0] = *(const float4*)(att + off);
    *(float4*)&avf[4] = *(const float4*)(att + off + 4);
#if HAS_FDOT2
    half2v xr2[4], a06[4], a04[4];       // lrelu(v)*a = (0.6a)*v + (0.4a)*|v|
#pragma unroll
    for (int i = 0; i < 4; ++i) {
        xr2[i] = xru.h2[i];
        a06[i] = (half2v){(_Float16)(0.6f * avf[2 * i]), (_Float16)(0.6f * avf[2 * i + 1])};
        a04[i] = (half2v){(_Float16)(0.4f * avf[2 * i]), (_Float16)(0.4f * avf[2 * i + 1])};
    }
#else
    float xrf[8];
#pragma unroll
    for (int i = 0; i < 8; ++i) xrf[i] = (float)xru.h[i];
#endif
    const int e0 = row_ptr[d];
    const int deg = row_ptr[d + 1] - e0;
    const int cnt = deg + 1;             // + self loop at index deg
    const int nchunk = (cnt + 1) >> 1;   // 2 edges per chunk
    float m = -INFINITY, s_loc = 0.f;
    float acc8[8] = {0.f, 0.f, 0.f, 0.f, 0.f, 0.f, 0.f, 0.f};

    // ---- pipeline prologue: gather chunk 0, index for chunk 1 ----
    U8 gc;
    {
        const int j = e;
        const int sn = (j < deg) ? csr_src[e0 + j] : d;
        gc.u = *(const uint4*)(xl + (size_t)sn * 256 + off);
    }
    int sn_nxt = d;
    if (nchunk > 1) {
        const int j = 2 + e;
        sn_nxt = (j < deg) ? csr_src[e0 + j] : d;
    }

    for (int c = 0; c < nchunk; ++c) {
        const int base = c << 1;
        // prefetch: index for chunk c+2
        int sn_n2 = d;
        if (c + 2 < nchunk) {
            const int j = base + 4 + e;
            sn_n2 = (j < deg) ? csr_src[e0 + j] : d;
        }
        // prefetch: gather for chunk c+1
        U8 gn;
        gn.u = make_uint4(0, 0, 0, 0);
        if (c + 1 < nchunk) gn.u = *(const uint4*)(xl + (size_t)sn_nxt * 256 + off);

        // ---- compute on chunk c ----
        const int j = base + e;
        float sc = 0.f;
#if HAS_FDOT2
#pragma unroll
        for (int i = 0; i < 4; ++i) {
            half2v v = gc.h2[i] + xr2[i];                      // v_pk_add_f16
            unsigned vb = __builtin_bit_cast(unsigned, v);
            half2v va = __builtin_bit_cast(half2v, vb & 0x7fff7fffu);  // packed |v|
            sc = __builtin_amdgcn_fdot2(v, a06[i], sc, false);
            sc = __builtin_amdgcn_fdot2(va, a04[i], sc, false);
        }
#else
#pragma unroll
        for (int i = 0; i < 8; ++i) {
            float v = (float)gc.h[i] + xrf[i];
            v = fmaxf(v, NEG_SLOPE * v);
            sc = fmaf(v, avf[i], sc);
        }
#endif
        // reduce over the 8 channel-groups of this head
        sc += __shfl_xor(sc, 1, 64);
        sc += __shfl_xor(sc, 2, 64);
        sc += __shfl_xor(sc, 4, 64);     // lane holds full score of (edge j, its head)
        sc = (j < cnt) ? sc : -INFINITY; // mask pad edge
        // per-head chunk max over the 2 edge slots
        float mx = fmaxf(sc, __shfl_xor(sc, 32, 64));
        if (mx > m + 8.f) {              // defer-rescale: p bounded by e^8
            const float g2f = __expf(m - mx);
            s_loc *= g2f;
#pragma unroll
            for (int i = 0; i < 8; ++i) acc8[i] *= g2f;
            m = mx;
        }
        const float p = __expf(sc - m);  // pad -> 0
        s_loc += p;
#pragma unroll
        for (int i = 0; i < 8; ++i)      // fp16 src -> v_fma_mix
            acc8[i] = fmaf(p, (float)gc.h[i], acc8[i]);

        gc = gn;
        sn_nxt = sn_n2;
    }

    // reduce across the 2 edge slots (once per node)
    float s_tot = s_loc + __shfl_xor(s_loc, 32, 64);
#pragma unroll
    for (int i = 0; i < 8; ++i) acc8[i] += __shfl_xor(acc8[i], 32, 64);
    const float inv_s = 1.f / s_tot;
    float o8[8];
    const float* bp = bias + off;
#pragma unroll
    for (int i = 0; i < 8; ++i) o8[i] = acc8[i] * inv_s + bp[i];

    if (apply_elu) {
#pragma unroll
        for (int i = 0; i < 8; ++i) o8[i] = o8[i] > 0.f ? o8[i] : (__expf(o8[i]) - 1.f);
        if (e == 0) {                    // 32 lanes x 16B = 512B contiguous
            uint4 u;
            u.x = pack2bf(o8[0], o8[1]);
            u.y = pack2bf(o8[2], o8[3]);
            u.z = pack2bf(o8[4], o8[5]);
            u.w = pack2bf(o8[6], o8[7]);
            *(uint4*)(out_b + (size_t)d * 256 + off) = u;
        }
    } else {
        if (e == 0) {
            float* op = out + (size_t)d * 256 + off;
            *(float4*)op       = make_float4(o8[0], o8[1], o8[2], o8[3]);
            *(float4*)(op + 4) = make_float4(o8[4], o8[5], o8[6], o8[7]);
        }
        // fused row log_softmax over all 256 channels — pure shfl, no LDS
        float mx = o8[0];
#pragma unroll
        for (int i = 1; i < 8; ++i) mx = fmaxf(mx, o8[i]);
        mx = fmaxf(mx, __shfl_xor(mx, 1, 64));
        mx = fmaxf(mx, __shfl_xor(mx, 2, 64));
        mx = fmaxf(mx, __shfl_xor(mx, 4, 64));
        mx = fmaxf(mx, __shfl_xor(mx, 8, 64));
        mx = fmaxf(mx, __shfl_xor(mx, 16, 64));   // row max (o8 replicated across e)
        float se = 0.f;
#pragma unroll
        for (int i = 0; i < 8; ++i) se += __expf(o8[i] - mx);
        se += __shfl_xor(se, 1, 64);
        se += __shfl_xor(se, 2, 64);
        se += __shfl_xor(se, 4, 64);
        se += __shfl_xor(se, 8, 64);
        se += __shfl_xor(se, 16, 64);
        const float lg = mx + __logf(se);
        if (e == 0) {
            float* lp = out_ls + (size_t)d * 256 + off;
            *(float4*)lp       = make_float4(o8[0] - lg, o8[1] - lg, o8[2] - lg, o8[3] - lg);
            *(float4*)(lp + 4) = make_float4(o8[4] - lg, o8[5] - lg, o8[6] - lg, o8[7] - lg);
        }
    }
}

extern "C" void kernel_launch(void* const* d_in, const int* in_sizes, int n_in,
                              void* d_out, int out_size, void* d_ws, size_t ws_size,
                              hipStream_t stream) {
    const float* x     = (const float*)d_in[0];
    const int*   edge  = (const int*)d_in[1];
    const float* Wl1   = (const float*)d_in[2];
    const float* bl1   = (const float*)d_in[3];
    const float* Wr1   = (const float*)d_in[4];
    const float* br1   = (const float*)d_in[5];
    const float* att1  = (const float*)d_in[6];
    const float* bias1 = (const float*)d_in[7];
    const float* Wl2   = (const float*)d_in[8];
    const float* bl2   = (const float*)d_in[9];
    const float* Wr2   = (const float*)d_in[10];
    const float* br2   = (const float*)d_in[11];
    const float* att2  = (const float*)d_in[12];
    const float* bias2 = (const float*)d_in[13];

    const int N = in_sizes[0] / 64;  // 20000
    const int E = in_sizes[1] / 2;   // 500000
    const int* srcI = edge;
    const int* dstI = edge + E;

    const size_t NM = (size_t)N * 256;
    _Float16*  XR   = (_Float16*)d_ws;             // NM fp16 (xr)
    ushort_t*  XB   = (ushort_t*)(XR + NM);        // NM bf16 (layer-1 out = layer-2 A)
    _Float16*  XL   = (_Float16*)(XB + NM);        // NM fp16 (xl gather table)
    ushort_t*  WT1l = (ushort_t*)(XL + NM);        // 256*64
    ushort_t*  WT1r = WT1l + 256 * 64;             // 256*64
    ushort_t*  WT2l = WT1r + 256 * 64;             // 256*256
    ushort_t*  WT2r = WT2l + 256 * 256;            // 256*256
    int* deg     = (int*)(WT2r + 256 * 256);       // N
    int* row_ptr = deg + N;                        // N+1
    int* cursor  = row_ptr + N + 1;                // N
    int* partial = cursor + N;                     // nb
    int* blk_off = partial + ((N + 255) / 256);      // nb+1
    int* csr_src = blk_off + ((N + 255) / 256) + 1;  // E

    const int nb = (N + 255) / 256;
    const int e_grid = (E + 255) / 256;
    const dim3 gemm_grid((N + 63) / 64, 2);
    const int gat_grid = (N + 1) / 2;

    // ---- weight transposes to bf16 (one launch) ----
    wt_all_kernel<<<640, 256, 0, stream>>>(Wl1, Wr1, Wl2, Wr2, WT1l, WT1r, WT2l, WT2r);

    // ---- CSR by destination ----
    hipMemsetAsync(deg, 0, (size_t)N * sizeof(int), stream);
    hipMemsetAsync(cursor, 0, (size_t)N * sizeof(int), stream);
    hist_kernel<<<e_grid, 256, 0, stream>>>(dstI, deg, E);
    partial_kernel<<<nb, 256, 0, stream>>>(deg, partial, N);
    scan_kernel<<<1, 1024, 0, stream>>>(partial, blk_off, nb);
    scan_block_kernel<<<nb, 256, 0, stream>>>(deg, blk_off, row_ptr, N);
    scatter_kernel<<<e_grid, 256, 0, stream>>>(srcI, dstI, row_ptr, cursor, csr_src, E);

    // ---- layer 1 (A = x fp32, K=64): one dual GEMM -> XL (fp16) + XR (fp16) ----
    gemm_dual_kernel<64, true><<<gemm_grid, 256, 0, stream>>>(x, WT1l, WT1r, bl1, br1,
                                                              XL, XR, N);
    gat_fused_kernel<<<gat_grid, 128, 0, stream>>>(csr_src, row_ptr, XL, XR, att1, bias1,
                                                   XB, nullptr, nullptr, N, 1);

    // ---- layer 2 (A = XB bf16, K=256) ----
    gemm_dual_kernel<256, false><<<gemm_grid, 256, 0, stream>>>(XB, WT2l, WT2r, bl2, br2,
                                                                XL, XR, N);
    float* h2 = (float*)d_out;
    gat_fused_kernel<<<gat_grid, 128, 0, stream>>>(csr_src, row_ptr, XL, XR, att2, bias2,
                                                   nullptr, h2, h2 + NM, N, 0);
}

// Round 14
// 200.599 us; speedup vs baseline: 1.5523x; 1.0392x over previous
//
#include <hip/hip_runtime.h>
#include <math.h>

#define NEG_SLOPE 0.2f

typedef unsigned short ushort_t;
typedef __attribute__((ext_vector_type(8))) short short8;
typedef __attribute__((ext_vector_type(4))) float float4v;
typedef _Float16 half2v __attribute__((ext_vector_type(2)));

#if defined(__has_builtin)
#if __has_builtin(__builtin_amdgcn_fdot2)
#define HAS_FDOT2 1
#endif
#if __has_builtin(__builtin_amdgcn_update_dpp)
#define HAS_DPP 1
#endif
#endif

__device__ __forceinline__ ushort_t f2bf(float f) {           // RNE
    unsigned u = __float_as_uint(f);
    return (ushort_t)((u + 0x7fffu + ((u >> 16) & 1u)) >> 16);
}
__device__ __forceinline__ unsigned pack2bf(float lo, float hi) {
    return ((unsigned)f2bf(hi) << 16) | (unsigned)f2bf(lo);
}

#if HAS_DPP
template <int CTRL>
__device__ __forceinline__ float dppf(float x) {   // bound_ctrl=1: OOB reads 0
    return __uint_as_float((unsigned)__builtin_amdgcn_update_dpp(
        0, (int)__float_as_uint(x), CTRL, 0xF, 0xF, true));
}
#endif

// ================= CSR build =================
__global__ void hist_kernel(const int* __restrict__ dst, int* __restrict__ deg, int E) {
    int i = blockIdx.x * 256 + threadIdx.x;
    if (i < E) atomicAdd(&deg[dst[i]], 1);
}

__global__ void partial_kernel(const int* __restrict__ deg, int* __restrict__ partial, int n) {
    const int t = threadIdx.x;
    const int i = blockIdx.x * 256 + t;
    int v = (i < n) ? deg[i] : 0;
#pragma unroll
    for (int off = 32; off > 0; off >>= 1) v += __shfl_xor(v, off, 64);
    __shared__ int ws[4];
    if ((t & 63) == 0) ws[t >> 6] = v;
    __syncthreads();
    if (t == 0) partial[blockIdx.x] = ws[0] + ws[1] + ws[2] + ws[3];
}

__global__ void scan_kernel(const int* __restrict__ in, int* __restrict__ out, int n) {
    __shared__ int sm[1024];
    __shared__ int carry_s;
    const int t = threadIdx.x;
    if (t == 0) { carry_s = 0; out[0] = 0; }
    __syncthreads();
    for (int base = 0; base < n; base += 1024) {
        int v = (base + t < n) ? in[base + t] : 0;
        sm[t] = v;
        __syncthreads();
        for (int off = 1; off < 1024; off <<= 1) {
            int u = (t >= off) ? sm[t - off] : 0;
            __syncthreads();
            sm[t] += u;
            __syncthreads();
        }
        if (base + t < n) out[base + t + 1] = carry_s + sm[t];
        __syncthreads();
        if (t == 0) carry_s += sm[1023];
        __syncthreads();
    }
}

__global__ void scan_block_kernel(const int* __restrict__ deg, const int* __restrict__ blk_off,
                                  int* __restrict__ row_ptr, int n) {
    const int t = threadIdx.x;
    const int i = blockIdx.x * 256 + t;
    const int lane = t & 63, w = t >> 6;
    int x = (i < n) ? deg[i] : 0;
#pragma unroll
    for (int off = 1; off < 64; off <<= 1) {
        int u = __shfl_up(x, off, 64);
        if (lane >= off) x += u;
    }
    __shared__ int ws[4];
    if (lane == 63) ws[w] = x;
    __syncthreads();
    int add = blk_off[blockIdx.x];
#pragma unroll
    for (int j = 0; j < 4; ++j)
        if (j < w) add += ws[j];
    if (i < n) row_ptr[i + 1] = add + x;
    if (i == 0) row_ptr[0] = 0;
}

__global__ void scatter_kernel(const int* __restrict__ src, const int* __restrict__ dst,
                               const int* __restrict__ row_ptr, int* __restrict__ cursor,
                               int* __restrict__ csr_src, int E) {
    int i = blockIdx.x * 256 + threadIdx.x;
    if (i < E) {
        int d = dst[i];
        int pos = row_ptr[d] + atomicAdd(&cursor[d], 1);
        csr_src[pos] = src[i];
    }
}

// ======= all four weight transposes in ONE launch: WT[c][k] = bf16(W[k][c]) =======
__global__ void wt_all_kernel(const float* __restrict__ W1l, const float* __restrict__ W1r,
                              const float* __restrict__ W2l, const float* __restrict__ W2r,
                              ushort_t* __restrict__ T1l, ushort_t* __restrict__ T1r,
                              ushort_t* __restrict__ T2l, ushort_t* __restrict__ T2r) {
    const int b = blockIdx.x;
    const float* W;
    ushort_t* T;
    int K, idx;
    if (b < 64)       { W = W1l; T = T1l; K = 64;  idx = b * 256 + threadIdx.x; }
    else if (b < 128) { W = W1r; T = T1r; K = 64;  idx = (b - 64) * 256 + threadIdx.x; }
    else if (b < 384) { W = W2l; T = T2l; K = 256; idx = (b - 128) * 256 + threadIdx.x; }
    else              { W = W2r; T = T2r; K = 256; idx = (b - 384) * 256 + threadIdx.x; }
    const int k = idx >> 8, c = idx & 255;
    T[(size_t)c * K + k] = f2bf(W[idx]);
}

// ====== dual MFMA GEMM (double-buffered LDS): outl/outr both fp16 ==================
template <int K, bool A_FP32>
__global__ __launch_bounds__(256) void gemm_dual_kernel(const void* __restrict__ Av,
                                                        const ushort_t* __restrict__ BTl,
                                                        const ushort_t* __restrict__ BTr,
                                                        const float* __restrict__ bl,
                                                        const float* __restrict__ br,
                                                        _Float16* __restrict__ outl,
                                                        _Float16* __restrict__ outr, int M) {
    __shared__ ushort_t As[2][64][40];       // [buf][row][k]
    __shared__ ushort_t Bs[2][2][128][40];   // [buf][mat][col][k]
    const int t = threadIdx.x;
    const int row0 = blockIdx.x * 64, col0 = blockIdx.y * 128;
    const int wid = t >> 6, lane = t & 63;
    const int wr = wid >> 1, wc = wid & 1;
    const int frow = lane & 15, fk = (lane >> 4) * 8;
    const int arow = t >> 2, ak8 = (t & 3) * 8;
    const int srow = t >> 1, sks = (t & 1) * 16;

    float4v acc[2][2][4];
#pragma unroll
    for (int m = 0; m < 2; ++m)
#pragma unroll
        for (int i = 0; i < 2; ++i)
#pragma unroll
            for (int j = 0; j < 4; ++j) acc[m][i][j] = (float4v){0.f, 0.f, 0.f, 0.f};

    auto stage = [&](int buf, int k0) {
        uint4 va = make_uint4(0, 0, 0, 0);
        if (row0 + arow < M) {
            if (A_FP32) {
                const float* Xf = (const float*)Av + (size_t)(row0 + arow) * K + k0 + ak8;
                float4 x0 = *(const float4*)(Xf + 0);
                float4 x1 = *(const float4*)(Xf + 4);
                va = make_uint4(pack2bf(x0.x, x0.y), pack2bf(x0.z, x0.w),
                                pack2bf(x1.x, x1.y), pack2bf(x1.z, x1.w));
            } else {
                va = *(const uint4*)((const ushort_t*)Av + (size_t)(row0 + arow) * K + k0 + ak8);
            }
        }
        *(uint4*)&As[buf][arow][ak8] = va;
        const ushort_t* Bp = BTl + (size_t)(col0 + srow) * K + k0 + sks;
        *(uint4*)&Bs[buf][0][srow][sks + 0] = *(const uint4*)(Bp + 0);
        *(uint4*)&Bs[buf][0][srow][sks + 8] = *(const uint4*)(Bp + 8);
        const ushort_t* Bq = BTr + (size_t)(col0 + srow) * K + k0 + sks;
        *(uint4*)&Bs[buf][1][srow][sks + 0] = *(const uint4*)(Bq + 0);
        *(uint4*)&Bs[buf][1][srow][sks + 8] = *(const uint4*)(Bq + 8);
    };

    stage(0, 0);
    __syncthreads();
    int cur = 0;
    for (int k0 = 0; k0 < K; k0 += 32) {
        if (k0 + 32 < K) stage(cur ^ 1, k0 + 32);   // loads hide under MFMA below
        short8 af[2], bf[2][4];
#pragma unroll
        for (int mi = 0; mi < 2; ++mi)
            af[mi] = *(const short8*)&As[cur][wr * 32 + mi * 16 + frow][fk];
#pragma unroll
        for (int m = 0; m < 2; ++m)
#pragma unroll
            for (int ni = 0; ni < 4; ++ni)
                bf[m][ni] = *(const short8*)&Bs[cur][m][wc * 64 + ni * 16 + frow][fk];
#pragma unroll
        for (int m = 0; m < 2; ++m)
#pragma unroll
            for (int mi = 0; mi < 2; ++mi)
#pragma unroll
                for (int ni = 0; ni < 4; ++ni)
                    acc[m][mi][ni] = __builtin_amdgcn_mfma_f32_16x16x32_bf16(
                        af[mi], bf[m][ni], acc[m][mi][ni], 0, 0, 0);
        __syncthreads();
        cur ^= 1;
    }

    const int crow = (lane >> 4) * 4;
#pragma unroll
    for (int ni = 0; ni < 4; ++ni) {
        const int col = col0 + wc * 64 + ni * 16 + frow;
        const float bvl = bl[col], bvr = br[col];
#pragma unroll
        for (int mi = 0; mi < 2; ++mi) {
#pragma unroll
            for (int r = 0; r < 4; ++r) {
                const int row = row0 + wr * 32 + mi * 16 + crow + r;
                if (row < M) {
                    outl[(size_t)row * 256 + col] = (_Float16)(acc[0][mi][ni][r] + bvl);
                    outr[(size_t)row * 256 + col] = (_Float16)(acc[1][mi][ni][r] + bvr);
                }
            }
        }
    }
}

// ============ fused GAT: ONE WAVE per node, quad_perm DPP + 1 shfl reduce ===========
// lane = e*32 + g: e = edge slot 0..1, g = channel group 0..31 (head = g>>3).
__global__ __launch_bounds__(128) void gat_fused_kernel(const int* __restrict__ csr_src,
                                                        const int* __restrict__ row_ptr,
                                                        const _Float16* __restrict__ xl,
                                                        const _Float16* __restrict__ xr,
                                                        const float* __restrict__ att,
                                                        const float* __restrict__ bias,
                                                        ushort_t* __restrict__ out_b,
                                                        float* __restrict__ out,
                                                        float* __restrict__ out_ls,
                                                        int n_nodes, int apply_elu) {
    const int wv = threadIdx.x >> 6;
    const int d = blockIdx.x * 2 + wv;
    if (d >= n_nodes) return;            // wave-uniform, no barriers anywhere
    const int lane = threadIdx.x & 63;
    const int e = lane >> 5;             // edge slot 0..1
    const int g = lane & 31;             // channel group (covers all 4 heads)
    const int off = g * 8;               // flat channel offset 0..255 step 8

    union U8 { uint4 u; _Float16 h[8]; half2v h2[4]; };
    U8 xru;
    xru.u = *(const uint4*)(xr + (size_t)d * 256 + off);
    float avf[8];
    *(float4*)&avf[0] = *(const float4*)(att + off);
    *(float4*)&avf[4] = *(const float4*)(att + off + 4);
#if HAS_FDOT2
    half2v xr2[4], a06[4], a04[4];       // lrelu(v)*a = (0.6a)*v + (0.4a)*|v|
#pragma unroll
    for (int i = 0; i < 4; ++i) {
        xr2[i] = xru.h2[i];
        a06[i] = (half2v){(_Float16)(0.6f * avf[2 * i]), (_Float16)(0.6f * avf[2 * i + 1])};
        a04[i] = (half2v){(_Float16)(0.4f * avf[2 * i]), (_Float16)(0.4f * avf[2 * i + 1])};
    }
#else
    float xrf[8];
#pragma unroll
    for (int i = 0; i < 8; ++i) xrf[i] = (float)xru.h[i];
#endif
    const int e0 = row_ptr[d];
    const int deg = row_ptr[d + 1] - e0;
    const int cnt = deg + 1;             // + self loop at index deg
    const int nchunk = (cnt + 1) >> 1;   // 2 edges per chunk
    float m = -INFINITY, s_loc = 0.f;
    float acc8[8] = {0.f, 0.f, 0.f, 0.f, 0.f, 0.f, 0.f, 0.f};

    // ---- pipeline prologue: gather chunk 0, index for chunk 1 ----
    U8 gc;
    {
        const int j = e;
        const int sn = (j < deg) ? csr_src[e0 + j] : d;
        gc.u = *(const uint4*)(xl + (size_t)sn * 256 + off);
    }
    int sn_nxt = d;
    if (nchunk > 1) {
        const int j = 2 + e;
        sn_nxt = (j < deg) ? csr_src[e0 + j] : d;
    }

    for (int c = 0; c < nchunk; ++c) {
        const int base = c << 1;
        // prefetch: index for chunk c+2
        int sn_n2 = d;
        if (c + 2 < nchunk) {
            const int j = base + 4 + e;
            sn_n2 = (j < deg) ? csr_src[e0 + j] : d;
        }
        // prefetch: gather for chunk c+1
        U8 gn;
        gn.u = make_uint4(0, 0, 0, 0);
        if (c + 1 < nchunk) gn.u = *(const uint4*)(xl + (size_t)sn_nxt * 256 + off);

        // ---- compute on chunk c ----
        const int j = base + e;
        float sc = 0.f;
#if HAS_FDOT2
#pragma unroll
        for (int i = 0; i < 4; ++i) {
            half2v v = gc.h2[i] + xr2[i];                      // v_pk_add_f16
            unsigned vb = __builtin_bit_cast(unsigned, v);
            half2v va = __builtin_bit_cast(half2v, vb & 0x7fff7fffu);  // packed |v|
            sc = __builtin_amdgcn_fdot2(v, a06[i], sc, false);
            sc = __builtin_amdgcn_fdot2(va, a04[i], sc, false);
        }
#else
#pragma unroll
        for (int i = 0; i < 8; ++i) {
            float v = (float)gc.h[i] + xrf[i];
            v = fmaxf(v, NEG_SLOPE * v);
            sc = fmaf(v, avf[i], sc);
        }
#endif
        // ---- reduce over the 8 channel-groups: quad_perm DPP (xor1,xor2) + shfl xor4
#if HAS_DPP
        sc += dppf<0xB1>(sc);            // quad_perm [1,0,3,2] = xor1 (unambiguous)
        sc += dppf<0x4E>(sc);            // quad_perm [2,3,0,1] = xor2 (unambiguous)
#else
        sc += __shfl_xor(sc, 1, 64);
        sc += __shfl_xor(sc, 2, 64);
#endif
        sc += __shfl_xor(sc, 4, 64);     // xor4 (ds_bpermute, guaranteed correct)
        sc = (j < cnt) ? sc : -INFINITY; // mask pad edge
        // per-head chunk max over the 2 edge slots
        float mx = fmaxf(sc, __shfl_xor(sc, 32, 64));
        if (mx > m + 8.f) {              // defer-rescale: p bounded by e^8
            const float g2f = __expf(m - mx);
            s_loc *= g2f;
#pragma unroll
            for (int i = 0; i < 8; ++i) acc8[i] *= g2f;
            m = mx;
        }
        const float p = __expf(sc - m);  // pad -> 0
        s_loc += p;
#pragma unroll
        for (int i = 0; i < 8; ++i)      // fp16 src -> v_fma_mix
            acc8[i] = fmaf(p, (float)gc.h[i], acc8[i]);

        gc = gn;
        sn_nxt = sn_n2;
    }

    // reduce across the 2 edge slots (once per node)
    float s_tot = s_loc + __shfl_xor(s_loc, 32, 64);
#pragma unroll
    for (int i = 0; i < 8; ++i) acc8[i] += __shfl_xor(acc8[i], 32, 64);
    const float inv_s = 1.f / s_tot;
    float o8[8];
    const float* bp = bias + off;
#pragma unroll
    for (int i = 0; i < 8; ++i) o8[i] = acc8[i] * inv_s + bp[i];

    if (apply_elu) {
#pragma unroll
        for (int i = 0; i < 8; ++i) o8[i] = o8[i] > 0.f ? o8[i] : (__expf(o8[i]) - 1.f);
        if (e == 0) {                    // 32 lanes x 16B = 512B contiguous
            uint4 u;
            u.x = pack2bf(o8[0], o8[1]);
            u.y = pack2bf(o8[2], o8[3]);
            u.z = pack2bf(o8[4], o8[5]);
            u.w = pack2bf(o8[6], o8[7]);
            *(uint4*)(out_b + (size_t)d * 256 + off) = u;
        }
    } else {
        if (e == 0) {
            float* op = out + (size_t)d * 256 + off;
            *(float4*)op       = make_float4(o8[0], o8[1], o8[2], o8[3]);
            *(float4*)(op + 4) = make_float4(o8[4], o8[5], o8[6], o8[7]);
        }
        // fused row log_softmax over all 256 channels — pure shfl, no LDS
        float mx = o8[0];
#pragma unroll
        for (int i = 1; i < 8; ++i) mx = fmaxf(mx, o8[i]);
        mx = fmaxf(mx, __shfl_xor(mx, 1, 64));
        mx = fmaxf(mx, __shfl_xor(mx, 2, 64));
        mx = fmaxf(mx, __shfl_xor(mx, 4, 64));
        mx = fmaxf(mx, __shfl_xor(mx, 8, 64));
        mx = fmaxf(mx, __shfl_xor(mx, 16, 64));   // row max (o8 replicated across e)
        float se = 0.f;
#pragma unroll
        for (int i = 0; i < 8; ++i) se += __expf(o8[i] - mx);
        se += __shfl_xor(se, 1, 64);
        se += __shfl_xor(se, 2, 64);
        se += __shfl_xor(se, 4, 64);
        se += __shfl_xor(se, 8, 64);
        se += __shfl_xor(se, 16, 64);
        const float lg = mx + __logf(se);
        if (e == 0) {
            float* lp = out_ls + (size_t)d * 256 + off;
            *(float4*)lp       = make_float4(o8[0] - lg, o8[1] - lg, o8[2] - lg, o8[3] - lg);
            *(float4*)(lp + 4) = make_float4(o8[4] - lg, o8[5] - lg, o8[6] - lg, o8[7] - lg);
        }
    }
}

extern "C" void kernel_launch(void* const* d_in, const int* in_sizes, int n_in,
                              void* d_out, int out_size, void* d_ws, size_t ws_size,
                              hipStream_t stream) {
    const float* x     = (const float*)d_in[0];
    const int*   edge  = (const int*)d_in[1];
    const float* Wl1   = (const float*)d_in[2];
    const float* bl1   = (const float*)d_in[3];
    const float* Wr1   = (const float*)d_in[4];
    const float* br1   = (const float*)d_in[5];
    const float* att1  = (const float*)d_in[6];
    const float* bias1 = (const float*)d_in[7];
    const float* Wl2   = (const float*)d_in[8];
    const float* bl2   = (const float*)d_in[9];
    const float* Wr2   = (const float*)d_in[10];
    const float* br2   = (const float*)d_in[11];
    const float* att2  = (const float*)d_in[12];
    const float* bias2 = (const float*)d_in[13];

    const int N = in_sizes[0] / 64;  // 20000
    const int E = in_sizes[1] / 2;   // 500000
    const int* srcI = edge;
    const int* dstI = edge + E;

    const size_t NM = (size_t)N * 256;
    _Float16*  XR   = (_Float16*)d_ws;             // NM fp16 (xr)
    ushort_t*  XB   = (ushort_t*)(XR + NM);        // NM bf16 (layer-1 out = layer-2 A)
    _Float16*  XL   = (_Float16*)(XB + NM);        // NM fp16 (xl gather table)
    ushort_t*  WT1l = (ushort_t*)(XL + NM);        // 256*64
    ushort_t*  WT1r = WT1l + 256 * 64;             // 256*64
    ushort_t*  WT2l = WT1r + 256 * 64;             // 256*256
    ushort_t*  WT2r = WT2l + 256 * 256;            // 256*256
    int* deg     = (int*)(WT2r + 256 * 256);       // N   (deg+cursor adjacent: 1 memset)
    int* cursor  = deg + N;                        // N
    int* row_ptr = cursor + N;                     // N+1
    int* partial = row_ptr + N + 1;                // nb
    int* blk_off = partial + ((N + 255) / 256);      // nb+1
    int* csr_src = blk_off + ((N + 255) / 256) + 1;  // E

    const int nb = (N + 255) / 256;
    const int e_grid = (E + 255) / 256;
    const dim3 gemm_grid((N + 63) / 64, 2);
    const int gat_grid = (N + 1) / 2;

    // ---- weight transposes to bf16 (one launch) ----
    wt_all_kernel<<<640, 256, 0, stream>>>(Wl1, Wr1, Wl2, Wr2, WT1l, WT1r, WT2l, WT2r);

    // ---- CSR by destination ----
    hipMemsetAsync(deg, 0, (size_t)(2 * N) * sizeof(int), stream);  // deg + cursor
    hist_kernel<<<e_grid, 256, 0, stream>>>(dstI, deg, E);
    partial_kernel<<<nb, 256, 0, stream>>>(deg, partial, N);
    scan_kernel<<<1, 1024, 0, stream>>>(partial, blk_off, nb);
    scan_block_kernel<<<nb, 256, 0, stream>>>(deg, blk_off, row_ptr, N);
    scatter_kernel<<<e_grid, 256, 0, stream>>>(srcI, dstI, row_ptr, cursor, csr_src, E);

    // ---- layer 1 (A = x fp32, K=64): one dual GEMM -> XL (fp16) + XR (fp16) ----
    gemm_dual_kernel<64, true><<<gemm_grid, 256, 0, stream>>>(x, WT1l, WT1r, bl1, br1,
                                                              XL, XR, N);
    gat_fused_kernel<<<gat_grid, 128, 0, stream>>>(csr_src, row_ptr, XL, XR, att1, bias1,
                                                   XB, nullptr, nullptr, N, 1);

    // ---- layer 2 (A = XB bf16, K=256) ----
    gemm_dual_kernel<256, false><<<gemm_grid, 256, 0, stream>>>(XB, WT2l, WT2r, bl2, br2,
                                                                XL, XR, N);
    float* h2 = (float*)d_out;
    gat_fused_kernel<<<gat_grid, 128, 0, stream>>>(csr_src, row_ptr, XL, XR, att2, bias2,
                                                   nullptr, h2, h2 + NM, N, 0);
}

// Round 15
// 196.999 us; speedup vs baseline: 1.5806x; 1.0183x over previous
//
#include <hip/hip_runtime.h>
#include <math.h>

#define NEG_SLOPE 0.2f

typedef unsigned short ushort_t;
typedef __attribute__((ext_vector_type(8))) short short8;
typedef __attribute__((ext_vector_type(4))) float float4v;
typedef _Float16 half2v __attribute__((ext_vector_type(2)));

#if defined(__has_builtin)
#if __has_builtin(__builtin_amdgcn_fdot2)
#define HAS_FDOT2 1
#endif
#if __has_builtin(__builtin_amdgcn_update_dpp)
#define HAS_DPP 1
#endif
#endif

__device__ __forceinline__ ushort_t f2bf(float f) {           // RNE
    unsigned u = __float_as_uint(f);
    return (ushort_t)((u + 0x7fffu + ((u >> 16) & 1u)) >> 16);
}
__device__ __forceinline__ unsigned pack2bf(float lo, float hi) {
    return ((unsigned)f2bf(hi) << 16) | (unsigned)f2bf(lo);
}

#if HAS_DPP
template <int CTRL>
__device__ __forceinline__ float dppf(float x) {   // bound_ctrl=1: OOB reads 0
    return __uint_as_float((unsigned)__builtin_amdgcn_update_dpp(
        0, (int)__float_as_uint(x), CTRL, 0xF, 0xF, true));
}
#endif

// ================= CSR build =================
__global__ void hist_kernel(const int* __restrict__ dst, int* __restrict__ deg, int E) {
    int i = blockIdx.x * 256 + threadIdx.x;
    if (i < E) atomicAdd(&deg[dst[i]], 1);
}

__global__ void partial_kernel(const int* __restrict__ deg, int* __restrict__ partial, int n) {
    const int t = threadIdx.x;
    const int i = blockIdx.x * 256 + t;
    int v = (i < n) ? deg[i] : 0;
#pragma unroll
    for (int off = 32; off > 0; off >>= 1) v += __shfl_xor(v, off, 64);
    __shared__ int ws[4];
    if ((t & 63) == 0) ws[t >> 6] = v;
    __syncthreads();
    if (t == 0) partial[blockIdx.x] = ws[0] + ws[1] + ws[2] + ws[3];
}

__global__ void scan_kernel(const int* __restrict__ in, int* __restrict__ out, int n) {
    __shared__ int sm[1024];
    __shared__ int carry_s;
    const int t = threadIdx.x;
    if (t == 0) { carry_s = 0; out[0] = 0; }
    __syncthreads();
    for (int base = 0; base < n; base += 1024) {
        int v = (base + t < n) ? in[base + t] : 0;
        sm[t] = v;
        __syncthreads();
        for (int off = 1; off < 1024; off <<= 1) {
            int u = (t >= off) ? sm[t - off] : 0;
            __syncthreads();
            sm[t] += u;
            __syncthreads();
        }
        if (base + t < n) out[base + t + 1] = carry_s + sm[t];
        __syncthreads();
        if (t == 0) carry_s += sm[1023];
        __syncthreads();
    }
}

__global__ void scan_block_kernel(const int* __restrict__ deg, const int* __restrict__ blk_off,
                                  int* __restrict__ row_ptr, int n) {
    const int t = threadIdx.x;
    const int i = blockIdx.x * 256 + t;
    const int lane = t & 63, w = t >> 6;
    int x = (i < n) ? deg[i] : 0;
#pragma unroll
    for (int off = 1; off < 64; off <<= 1) {
        int u = __shfl_up(x, off, 64);
        if (lane >= off) x += u;
    }
    __shared__ int ws[4];
    if (lane == 63) ws[w] = x;
    __syncthreads();
    int add = blk_off[blockIdx.x];
#pragma unroll
    for (int j = 0; j < 4; ++j)
        if (j < w) add += ws[j];
    if (i < n) row_ptr[i + 1] = add + x;
    if (i == 0) row_ptr[0] = 0;
}

__global__ void scatter_kernel(const int* __restrict__ src, const int* __restrict__ dst,
                               const int* __restrict__ row_ptr, int* __restrict__ cursor,
                               int* __restrict__ csr_src, int E) {
    int i = blockIdx.x * 256 + threadIdx.x;
    if (i < E) {
        int d = dst[i];
        int pos = row_ptr[d] + atomicAdd(&cursor[d], 1);
        csr_src[pos] = src[i];
    }
}

// ======= all four weight transposes in ONE launch: WT[c][k] = bf16(W[k][c]) =======
__global__ void wt_all_kernel(const float* __restrict__ W1l, const float* __restrict__ W1r,
                              const float* __restrict__ W2l, const float* __restrict__ W2r,
                              ushort_t* __restrict__ T1l, ushort_t* __restrict__ T1r,
                              ushort_t* __restrict__ T2l, ushort_t* __restrict__ T2r) {
    const int b = blockIdx.x;
    const float* W;
    ushort_t* T;
    int K, idx;
    if (b < 64)       { W = W1l; T = T1l; K = 64;  idx = b * 256 + threadIdx.x; }
    else if (b < 128) { W = W1r; T = T1r; K = 64;  idx = (b - 64) * 256 + threadIdx.x; }
    else if (b < 384) { W = W2l; T = T2l; K = 256; idx = (b - 128) * 256 + threadIdx.x; }
    else              { W = W2r; T = T2r; K = 256; idx = (b - 384) * 256 + threadIdx.x; }
    const int k = idx >> 8, c = idx & 255;
    T[(size_t)c * K + k] = f2bf(W[idx]);
}

// ====== dual MFMA GEMM (double-buffered LDS): outl/outr both fp16 ==================
template <int K, bool A_FP32>
__global__ __launch_bounds__(256) void gemm_dual_kernel(const void* __restrict__ Av,
                                                        const ushort_t* __restrict__ BTl,
                                                        const ushort_t* __restrict__ BTr,
                                                        const float* __restrict__ bl,
                                                        const float* __restrict__ br,
                                                        _Float16* __restrict__ outl,
                                                        _Float16* __restrict__ outr, int M) {
    __shared__ ushort_t As[2][64][40];       // [buf][row][k]
    __shared__ ushort_t Bs[2][2][128][40];   // [buf][mat][col][k]
    const int t = threadIdx.x;
    const int row0 = blockIdx.x * 64, col0 = blockIdx.y * 128;
    const int wid = t >> 6, lane = t & 63;
    const int wr = wid >> 1, wc = wid & 1;
    const int frow = lane & 15, fk = (lane >> 4) * 8;
    const int arow = t >> 2, ak8 = (t & 3) * 8;
    const int srow = t >> 1, sks = (t & 1) * 16;

    float4v acc[2][2][4];
#pragma unroll
    for (int m = 0; m < 2; ++m)
#pragma unroll
        for (int i = 0; i < 2; ++i)
#pragma unroll
            for (int j = 0; j < 4; ++j) acc[m][i][j] = (float4v){0.f, 0.f, 0.f, 0.f};

    auto stage = [&](int buf, int k0) {
        uint4 va = make_uint4(0, 0, 0, 0);
        if (row0 + arow < M) {
            if (A_FP32) {
                const float* Xf = (const float*)Av + (size_t)(row0 + arow) * K + k0 + ak8;
                float4 x0 = *(const float4*)(Xf + 0);
                float4 x1 = *(const float4*)(Xf + 4);
                va = make_uint4(pack2bf(x0.x, x0.y), pack2bf(x0.z, x0.w),
                                pack2bf(x1.x, x1.y), pack2bf(x1.z, x1.w));
            } else {
                va = *(const uint4*)((const ushort_t*)Av + (size_t)(row0 + arow) * K + k0 + ak8);
            }
        }
        *(uint4*)&As[buf][arow][ak8] = va;
        const ushort_t* Bp = BTl + (size_t)(col0 + srow) * K + k0 + sks;
        *(uint4*)&Bs[buf][0][srow][sks + 0] = *(const uint4*)(Bp + 0);
        *(uint4*)&Bs[buf][0][srow][sks + 8] = *(const uint4*)(Bp + 8);
        const ushort_t* Bq = BTr + (size_t)(col0 + srow) * K + k0 + sks;
        *(uint4*)&Bs[buf][1][srow][sks + 0] = *(const uint4*)(Bq + 0);
        *(uint4*)&Bs[buf][1][srow][sks + 8] = *(const uint4*)(Bq + 8);
    };

    stage(0, 0);
    __syncthreads();
    int cur = 0;
    for (int k0 = 0; k0 < K; k0 += 32) {
        if (k0 + 32 < K) stage(cur ^ 1, k0 + 32);   // loads hide under MFMA below
        short8 af[2], bf[2][4];
#pragma unroll
        for (int mi = 0; mi < 2; ++mi)
            af[mi] = *(const short8*)&As[cur][wr * 32 + mi * 16 + frow][fk];
#pragma unroll
        for (int m = 0; m < 2; ++m)
#pragma unroll
            for (int ni = 0; ni < 4; ++ni)
                bf[m][ni] = *(const short8*)&Bs[cur][m][wc * 64 + ni * 16 + frow][fk];
#pragma unroll
        for (int m = 0; m < 2; ++m)
#pragma unroll
            for (int mi = 0; mi < 2; ++mi)
#pragma unroll
                for (int ni = 0; ni < 4; ++ni)
                    acc[m][mi][ni] = __builtin_amdgcn_mfma_f32_16x16x32_bf16(
                        af[mi], bf[m][ni], acc[m][mi][ni], 0, 0, 0);
        __syncthreads();
        cur ^= 1;
    }

    const int crow = (lane >> 4) * 4;
#pragma unroll
    for (int ni = 0; ni < 4; ++ni) {
        const int col = col0 + wc * 64 + ni * 16 + frow;
        const float bvl = bl[col], bvr = br[col];
#pragma unroll
        for (int mi = 0; mi < 2; ++mi) {
#pragma unroll
            for (int r = 0; r < 4; ++r) {
                const int row = row0 + wr * 32 + mi * 16 + crow + r;
                if (row < M) {
                    outl[(size_t)row * 256 + col] = (_Float16)(acc[0][mi][ni][r] + bvl);
                    outr[(size_t)row * 256 + col] = (_Float16)(acc[1][mi][ni][r] + bvr);
                }
            }
        }
    }
}

// ============ fused GAT: ONE WAVE per node, 4 edge-slots x 16 ch-groups =============
// lane = e*16 + g: e = edge slot 0..3, g = channel group 0..15 (16 ch each).
// Head of lane = g>>2; a head's 4 partials live in ONE hardware quad -> pure
// quad_perm DPP score reduce (no bpermute). Chunk = 4 edges.
__global__ __launch_bounds__(128) void gat_fused_kernel(const int* __restrict__ csr_src,
                                                        const int* __restrict__ row_ptr,
                                                        const _Float16* __restrict__ xl,
                                                        const _Float16* __restrict__ xr,
                                                        const float* __restrict__ att,
                                                        const float* __restrict__ bias,
                                                        ushort_t* __restrict__ out_b,
                                                        float* __restrict__ out,
                                                        float* __restrict__ out_ls,
                                                        int n_nodes, int apply_elu) {
    const int wv = threadIdx.x >> 6;
    const int d = blockIdx.x * 2 + wv;
    if (d >= n_nodes) return;            // wave-uniform, no barriers anywhere
    const int lane = threadIdx.x & 63;
    const int e = lane >> 4;             // edge slot 0..3
    const int g = lane & 15;             // channel group (16 ch), head = g>>2
    const int off = g * 16;              // flat channel offset

    union U8 { uint4 u; _Float16 h[8]; half2v h2[4]; };
    U8 xr0, xr1;
    xr0.u = *(const uint4*)(xr + (size_t)d * 256 + off);
    xr1.u = *(const uint4*)(xr + (size_t)d * 256 + off + 8);
    float avf[16];
#pragma unroll
    for (int q = 0; q < 4; ++q)
        *(float4*)&avf[q * 4] = *(const float4*)(att + off + q * 4);
#if HAS_FDOT2
    half2v xr2[8], a06[8], a04[8];       // lrelu(v)*a = (0.6a)*v + (0.4a)*|v|
#pragma unroll
    for (int i = 0; i < 4; ++i) { xr2[i] = xr0.h2[i]; xr2[4 + i] = xr1.h2[i]; }
#pragma unroll
    for (int i = 0; i < 8; ++i) {
        a06[i] = (half2v){(_Float16)(0.6f * avf[2 * i]), (_Float16)(0.6f * avf[2 * i + 1])};
        a04[i] = (half2v){(_Float16)(0.4f * avf[2 * i]), (_Float16)(0.4f * avf[2 * i + 1])};
    }
#else
    float xrf[16];
#pragma unroll
    for (int i = 0; i < 8; ++i) { xrf[i] = (float)xr0.h[i]; xrf[8 + i] = (float)xr1.h[i]; }
#endif
    const int e0 = row_ptr[d];
    const int deg = row_ptr[d + 1] - e0;
    const int cnt = deg + 1;             // + self loop at index deg
    const int nchunk = (cnt + 3) >> 2;   // 4 edges per chunk
    float m = -INFINITY, s_loc = 0.f;
    float acc[16];
#pragma unroll
    for (int i = 0; i < 16; ++i) acc[i] = 0.f;

    // ---- pipeline prologue: gather chunk 0, index for chunk 1 ----
    U8 gc0, gc1;
    {
        const int j = e;
        const int sn = (j < deg) ? csr_src[e0 + j] : d;
        const _Float16* p = xl + (size_t)sn * 256 + off;
        gc0.u = *(const uint4*)p;
        gc1.u = *(const uint4*)(p + 8);
    }
    int sn_nxt = d;
    if (nchunk > 1) {
        const int j = 4 + e;
        sn_nxt = (j < deg) ? csr_src[e0 + j] : d;
    }

    for (int c = 0; c < nchunk; ++c) {
        const int base = c << 2;
        // prefetch: index for chunk c+2
        int sn_n2 = d;
        if (c + 2 < nchunk) {
            const int j = base + 8 + e;
            sn_n2 = (j < deg) ? csr_src[e0 + j] : d;
        }
        // prefetch: gather for chunk c+1 (2 loads in flight per lane)
        U8 gn0, gn1;
        gn0.u = make_uint4(0, 0, 0, 0);
        gn1.u = make_uint4(0, 0, 0, 0);
        if (c + 1 < nchunk) {
            const _Float16* p = xl + (size_t)sn_nxt * 256 + off;
            gn0.u = *(const uint4*)p;
            gn1.u = *(const uint4*)(p + 8);
        }

        // ---- compute on chunk c ----
        const int j = base + e;
        float sc = 0.f;
#if HAS_FDOT2
#pragma unroll
        for (int i = 0; i < 4; ++i) {
            half2v v = gc0.h2[i] + xr2[i];
            unsigned vb = __builtin_bit_cast(unsigned, v);
            half2v va = __builtin_bit_cast(half2v, vb & 0x7fff7fffu);
            sc = __builtin_amdgcn_fdot2(v, a06[i], sc, false);
            sc = __builtin_amdgcn_fdot2(va, a04[i], sc, false);
        }
#pragma unroll
        for (int i = 0; i < 4; ++i) {
            half2v v = gc1.h2[i] + xr2[4 + i];
            unsigned vb = __builtin_bit_cast(unsigned, v);
            half2v va = __builtin_bit_cast(half2v, vb & 0x7fff7fffu);
            sc = __builtin_amdgcn_fdot2(v, a06[4 + i], sc, false);
            sc = __builtin_amdgcn_fdot2(va, a04[4 + i], sc, false);
        }
#else
#pragma unroll
        for (int i = 0; i < 8; ++i) {
            float v = (float)gc0.h[i] + xrf[i];
            v = fmaxf(v, NEG_SLOPE * v);
            sc = fmaf(v, avf[i], sc);
        }
#pragma unroll
        for (int i = 0; i < 8; ++i) {
            float v = (float)gc1.h[i] + xrf[8 + i];
            v = fmaxf(v, NEG_SLOPE * v);
            sc = fmaf(v, avf[8 + i], sc);
        }
#endif
        // ---- head reduce: all within one hardware quad (pure DPP) ----
#if HAS_DPP
        sc += dppf<0xB1>(sc);            // quad_perm [1,0,3,2] = xor1
        sc += dppf<0x4E>(sc);            // quad_perm [2,3,0,1] = xor2
#else
        sc += __shfl_xor(sc, 1, 64);
        sc += __shfl_xor(sc, 2, 64);
#endif
        sc = (j < cnt) ? sc : -INFINITY; // mask pad edge
        // per-head chunk max across the 4 edge slots (lane bits 4,5)
        float mx = fmaxf(sc, __shfl_xor(sc, 16, 64));
        mx = fmaxf(mx, __shfl_xor(mx, 32, 64));
        if (mx > m + 8.f) {              // defer-rescale: p bounded by e^8
            const float g2f = __expf(m - mx);
            s_loc *= g2f;
#pragma unroll
            for (int i = 0; i < 16; ++i) acc[i] *= g2f;
            m = mx;
        }
        const float p = __expf(sc - m);  // pad -> 0
        s_loc += p;
#pragma unroll
        for (int i = 0; i < 8; ++i)      // fp16 src -> v_fma_mix
            acc[i] = fmaf(p, (float)gc0.h[i], acc[i]);
#pragma unroll
        for (int i = 0; i < 8; ++i)
            acc[8 + i] = fmaf(p, (float)gc1.h[i], acc[8 + i]);

        gc0 = gn0;
        gc1 = gn1;
        sn_nxt = sn_n2;
    }

    // reduce across the 4 edge slots (once per node)
    float s_tot = s_loc + __shfl_xor(s_loc, 16, 64);
    s_tot += __shfl_xor(s_tot, 32, 64);
#pragma unroll
    for (int i = 0; i < 16; ++i) {
        acc[i] += __shfl_xor(acc[i], 16, 64);
        acc[i] += __shfl_xor(acc[i], 32, 64);
    }
    const float inv_s = 1.f / s_tot;
    float o[16];
    const float* bp = bias + off;
#pragma unroll
    for (int i = 0; i < 16; ++i) o[i] = acc[i] * inv_s + bp[i];

    if (apply_elu) {
#pragma unroll
        for (int i = 0; i < 16; ++i) o[i] = o[i] > 0.f ? o[i] : (__expf(o[i]) - 1.f);
        if (e == 0) {                    // 16 lanes x 32B = 512B contiguous
            uint4 u0, u1;
            u0.x = pack2bf(o[0], o[1]);
            u0.y = pack2bf(o[2], o[3]);
            u0.z = pack2bf(o[4], o[5]);
            u0.w = pack2bf(o[6], o[7]);
            u1.x = pack2bf(o[8], o[9]);
            u1.y = pack2bf(o[10], o[11]);
            u1.z = pack2bf(o[12], o[13]);
            u1.w = pack2bf(o[14], o[15]);
            ushort_t* op = out_b + (size_t)d * 256 + off;
            *(uint4*)op       = u0;
            *(uint4*)(op + 8) = u1;
        }
    } else {
        if (e == 0) {
            float* op = out + (size_t)d * 256 + off;
#pragma unroll
            for (int q = 0; q < 4; ++q)
                *(float4*)(op + q * 4) = make_float4(o[q * 4], o[q * 4 + 1],
                                                     o[q * 4 + 2], o[q * 4 + 3]);
        }
        // fused row log_softmax over all 256 channels — values replicated across e
        float mx = o[0];
#pragma unroll
        for (int i = 1; i < 16; ++i) mx = fmaxf(mx, o[i]);
        mx = fmaxf(mx, __shfl_xor(mx, 1, 64));
        mx = fmaxf(mx, __shfl_xor(mx, 2, 64));
        mx = fmaxf(mx, __shfl_xor(mx, 4, 64));
        mx = fmaxf(mx, __shfl_xor(mx, 8, 64));
        float se = 0.f;
#pragma unroll
        for (int i = 0; i < 16; ++i) se += __expf(o[i] - mx);
        se += __shfl_xor(se, 1, 64);
        se += __shfl_xor(se, 2, 64);
        se += __shfl_xor(se, 4, 64);
        se += __shfl_xor(se, 8, 64);
        const float lg = mx + __logf(se);
        if (e == 0) {
            float* lp = out_ls + (size_t)d * 256 + off;
#pragma unroll
            for (int q = 0; q < 4; ++q)
                *(float4*)(lp + q * 4) = make_float4(o[q * 4] - lg, o[q * 4 + 1] - lg,
                                                     o[q * 4 + 2] - lg, o[q * 4 + 3] - lg);
        }
    }
}

extern "C" void kernel_launch(void* const* d_in, const int* in_sizes, int n_in,
                              void* d_out, int out_size, void* d_ws, size_t ws_size,
                              hipStream_t stream) {
    const float* x     = (const float*)d_in[0];
    const int*   edge  = (const int*)d_in[1];
    const float* Wl1   = (const float*)d_in[2];
    const float* bl1   = (const float*)d_in[3];
    const float* Wr1   = (const float*)d_in[4];
    const float* br1   = (const float*)d_in[5];
    const float* att1  = (const float*)d_in[6];
    const float* bias1 = (const float*)d_in[7];
    const float* Wl2   = (const float*)d_in[8];
    const float* bl2   = (const float*)d_in[9];
    const float* Wr2   = (const float*)d_in[10];
    const float* br2   = (const float*)d_in[11];
    const float* att2  = (const float*)d_in[12];
    const float* bias2 = (const float*)d_in[13];

    const int N = in_sizes[0] / 64;  // 20000
    const int E = in_sizes[1] / 2;   // 500000
    const int* srcI = edge;
    const int* dstI = edge + E;

    const size_t NM = (size_t)N * 256;
    _Float16*  XR   = (_Float16*)d_ws;             // NM fp16 (xr)
    ushort_t*  XB   = (ushort_t*)(XR + NM);        // NM bf16 (layer-1 out = layer-2 A)
    _Float16*  XL   = (_Float16*)(XB + NM);        // NM fp16 (xl gather table)
    ushort_t*  WT1l = (ushort_t*)(XL + NM);        // 256*64
    ushort_t*  WT1r = WT1l + 256 * 64;             // 256*64
    ushort_t*  WT2l = WT1r + 256 * 64;             // 256*256
    ushort_t*  WT2r = WT2l + 256 * 256;            // 256*256
    int* deg     = (int*)(WT2r + 256 * 256);       // N   (deg+cursor adjacent: 1 memset)
    int* cursor  = deg + N;                        // N
    int* row_ptr = cursor + N;                     // N+1
    int* partial = row_ptr + N + 1;                // nb
    int* blk_off = partial + ((N + 255) / 256);      // nb+1
    int* csr_src = blk_off + ((N + 255) / 256) + 1;  // E

    const int nb = (N + 255) / 256;
    const int e_grid = (E + 255) / 256;
    const dim3 gemm_grid((N + 63) / 64, 2);
    const int gat_grid = (N + 1) / 2;

    // ---- weight transposes to bf16 (one launch) ----
    wt_all_kernel<<<640, 256, 0, stream>>>(Wl1, Wr1, Wl2, Wr2, WT1l, WT1r, WT2l, WT2r);

    // ---- CSR by destination ----
    hipMemsetAsync(deg, 0, (size_t)(2 * N) * sizeof(int), stream);  // deg + cursor
    hist_kernel<<<e_grid, 256, 0, stream>>>(dstI, deg, E);
    partial_kernel<<<nb, 256, 0, stream>>>(deg, partial, N);
    scan_kernel<<<1, 1024, 0, stream>>>(partial, blk_off, nb);
    scan_block_kernel<<<nb, 256, 0, stream>>>(deg, blk_off, row_ptr, N);
    scatter_kernel<<<e_grid, 256, 0, stream>>>(srcI, dstI, row_ptr, cursor, csr_src, E);

    // ---- layer 1 (A = x fp32, K=64): one dual GEMM -> XL (fp16) + XR (fp16) ----
    gemm_dual_kernel<64, true><<<gemm_grid, 256, 0, stream>>>(x, WT1l, WT1r, bl1, br1,
                                                              XL, XR, N);
    gat_fused_kernel<<<gat_grid, 128, 0, stream>>>(csr_src, row_ptr, XL, XR, att1, bias1,
                                                   XB, nullptr, nullptr, N, 1);

    // ---- layer 2 (A = XB bf16, K=256) ----
    gemm_dual_kernel<256, false><<<gemm_grid, 256, 0, stream>>>(XB, WT2l, WT2r, bl2, br2,
                                                                XL, XR, N);
    float* h2 = (float*)d_out;
    gat_fused_kernel<<<gat_grid, 128, 0, stream>>>(csr_src, row_ptr, XL, XR, att2, bias2,
                                                   nullptr, h2, h2 + NM, N, 0);
}